// Round 1
// baseline (5727.062 us; speedup 1.0000x reference)
//
#include <hip/hip_runtime.h>
#include <hip/hip_bf16.h>

#define HID   1000
#define DICT  4811
#define TT    44
#define BB    256
#define K1    2000          // z1 K (xt | h1)
#define K2P   6816          // z2 K padded (prev | h2 | h1n | pad)
#define G4    4000          // 4*HID

typedef __attribute__((ext_vector_type(8))) short short8;
typedef __attribute__((ext_vector_type(4))) float f32x4;

__device__ __forceinline__ short f2b(float f) {
    unsigned u = __float_as_uint(f);
    unsigned r = (u + 0x7FFFu + ((u >> 16) & 1u)) >> 16;
    return (short)r;
}

// ---------------- prep kernels ----------------
__global__ void prep_w1(const float* __restrict__ wih1, const float* __restrict__ whh1,
                        short* __restrict__ w1cat) {
    for (size_t i = (size_t)blockIdx.x * blockDim.x + threadIdx.x; i < (size_t)G4 * K1;
         i += (size_t)gridDim.x * blockDim.x) {
        size_t n = i / K1, j = i % K1;
        float v = wih1[n * K1 + j];
        if (j >= HID) v += whh1[n * HID + (j - HID)];
        w1cat[i] = f2b(v);
    }
}

__global__ void prep_w2(const float* __restrict__ wih2, const float* __restrict__ whh2,
                        short* __restrict__ w2cat) {
    for (size_t i = (size_t)blockIdx.x * blockDim.x + threadIdx.x; i < (size_t)G4 * K2P;
         i += (size_t)gridDim.x * blockDim.x) {
        size_t n = i / K2P, j = i % K2P;
        float v = 0.f;
        if (j < DICT + 2 * HID) {
            v = wih2[n * (DICT + 2 * HID) + j];
            if (j >= DICT && j < DICT + HID) v += whh2[n * HID + (j - DICT)];
        }
        w2cat[i] = f2b(v);
    }
}

__global__ void prep_cvt(const float* __restrict__ src, short* __restrict__ dst, size_t n) {
    for (size_t i = (size_t)blockIdx.x * blockDim.x + threadIdx.x; i < n;
         i += (size_t)gridDim.x * blockDim.x)
        dst[i] = f2b(src[i]);
}

__global__ void prep_addv(const float* __restrict__ a, const float* __restrict__ b,
                          float* __restrict__ dst, int n) {
    int i = blockIdx.x * blockDim.x + threadIdx.x;
    if (i < n) dst[i] = a[i] + b[i];
}

__global__ void init_z1(const float* __restrict__ h1, short* __restrict__ z1) {
    int i = blockIdx.x * blockDim.x + threadIdx.x;
    if (i >= BB * K1) return;
    int b = i / K1, j = i % K1;
    z1[i] = (j < HID) ? (short)0 : f2b(h1[b * HID + (j - HID)]);
}

__global__ void init_z2(const float* __restrict__ h2, short* __restrict__ z2) {
    int i = blockIdx.x * blockDim.x + threadIdx.x;
    if (i >= BB * K2P) return;
    int b = i / K2P, j = i % K2P;
    float v = 0.f;
    if (j >= DICT && j < DICT + HID) v = h2[b * HID + (j - DICT)];
    z2[i] = (j >= DICT && j < DICT + HID) ? f2b(v) : (short)0;
}

__global__ void copy_xt(const short* __restrict__ xp, short* __restrict__ z1, int t) {
    int i = blockIdx.x * blockDim.x + threadIdx.x;
    if (i >= BB * HID) return;
    int b = i / HID, j = i % HID;
    z1[(size_t)b * K1 + j] = xp[((size_t)t * BB + b) * HID + j];
}

// ---------------- GEMM: C[M,N] = A[M,K] * B[N,K]^T  (bf16 in, fp32 acc) ----------------
// EPI 0: fp32 row-major store (+bias, part z==0 only);  EPI 1: bf16 scatter to xp[t][b][h]
template <int EPI, int AF32>
__global__ __launch_bounds__(256) void gemm_nt(
    const void* __restrict__ Ap, int lda,
    const short* __restrict__ Bp, int ldb,
    const float* __restrict__ bias,
    void* __restrict__ Cp, long long partStride, int ldc,
    int M, int N, int Kvalid)
{
    __shared__ short As[64][40];
    __shared__ short Bs[64][40];
    const int tid  = threadIdx.x;
    const int lane = tid & 63;
    const int wave = tid >> 6;
    const int wm = wave >> 1, wn = wave & 1;
    const int tm = blockIdx.y * 64, tn = blockIdx.x * 64;
    const int srow = tid >> 2;
    const int scol = (tid & 3) * 8;

    const int nk = (Kvalid + 31) >> 5;
    const int s0 = (int)(((long long)nk * blockIdx.z) / gridDim.z);
    const int s1 = (int)(((long long)nk * (blockIdx.z + 1)) / gridDim.z);

    const int arow = tm + srow;            // M always a multiple of 64 here
    const int brow = tn + srow;
    const bool bvalid = brow < N;

    auto loadA = [&](int ks) -> short8 {
        int k = (ks << 5) + scol;
        short8 r = {0, 0, 0, 0, 0, 0, 0, 0};
        if (k + 8 <= Kvalid) {
            if (AF32) {
                const f32x4* p = (const f32x4*)((const float*)Ap + (size_t)arow * lda + k);
                f32x4 u0 = p[0], u1 = p[1];
                r[0] = f2b(u0[0]); r[1] = f2b(u0[1]); r[2] = f2b(u0[2]); r[3] = f2b(u0[3]);
                r[4] = f2b(u1[0]); r[5] = f2b(u1[1]); r[6] = f2b(u1[2]); r[7] = f2b(u1[3]);
            } else {
                r = *(const short8*)((const short*)Ap + (size_t)arow * lda + k);
            }
        }
        return r;
    };
    auto loadB = [&](int ks) -> short8 {
        int k = (ks << 5) + scol;
        short8 r = {0, 0, 0, 0, 0, 0, 0, 0};
        if (bvalid && (k + 8 <= Kvalid))
            r = *(const short8*)(Bp + (size_t)brow * ldb + k);
        return r;
    };

    f32x4 acc[2][2];
    for (int a = 0; a < 2; ++a)
        for (int b = 0; b < 2; ++b)
            acc[a][b] = (f32x4){0.f, 0.f, 0.f, 0.f};

    short8 ra = loadA(s0), rb = loadB(s0);
    *(short8*)&As[srow][scol] = ra;
    *(short8*)&Bs[srow][scol] = rb;
    __syncthreads();

    const int kg = (lane >> 4) * 8;
    const int fr = lane & 15;

    for (int s = s0; s < s1; ++s) {
        short8 a0 = *(short8*)&As[wm * 32 + fr][kg];
        short8 a1 = *(short8*)&As[wm * 32 + 16 + fr][kg];
        short8 b0 = *(short8*)&Bs[wn * 32 + fr][kg];
        short8 b1 = *(short8*)&Bs[wn * 32 + 16 + fr][kg];
        short8 na, nb;
        if (s + 1 < s1) { na = loadA(s + 1); nb = loadB(s + 1); }
        acc[0][0] = __builtin_amdgcn_mfma_f32_16x16x32_bf16(a0, b0, acc[0][0], 0, 0, 0);
        acc[0][1] = __builtin_amdgcn_mfma_f32_16x16x32_bf16(a0, b1, acc[0][1], 0, 0, 0);
        acc[1][0] = __builtin_amdgcn_mfma_f32_16x16x32_bf16(a1, b0, acc[1][0], 0, 0, 0);
        acc[1][1] = __builtin_amdgcn_mfma_f32_16x16x32_bf16(a1, b1, acc[1][1], 0, 0, 0);
        __syncthreads();
        if (s + 1 < s1) {
            *(short8*)&As[srow][scol] = na;
            *(short8*)&Bs[srow][scol] = nb;
        }
        __syncthreads();
    }

    float* Cf = (float*)Cp + (size_t)partStride * blockIdx.z;
    for (int mi = 0; mi < 2; ++mi)
        for (int ni = 0; ni < 2; ++ni) {
            int col = tn + wn * 32 + ni * 16 + (lane & 15);
            if (col >= N) continue;
            float bv = bias ? bias[col] : 0.f;
            int row0 = tm + wm * 32 + mi * 16 + ((lane >> 4) << 2);
            f32x4 v = acc[mi][ni];
            for (int j = 0; j < 4; ++j) {
                int row = row0 + j;
                float val = v[j] + bv;
                if (EPI == 0) {
                    Cf[(size_t)row * ldc + col] = val;
                } else {
                    int b = row / TT, t = row % TT;  // x rows are (b,t) b-major
                    ((short*)Cp)[((size_t)t * BB + b) * ldc + col] = f2b(val);
                }
            }
        }
}

// ---------------- LSTM elementwise (sums 2 K-split gate parts) ----------------
__global__ void lstm_ew(const float* __restrict__ gA, const float* __restrict__ gB,
                        const float* __restrict__ bias, float* __restrict__ c,
                        short* __restrict__ d1, int ld1,
                        short* __restrict__ d2, int ld2)
{
    int i = blockIdx.x * blockDim.x + threadIdx.x;
    if (i >= BB * HID) return;
    int b = i / HID, h = i % HID;
    size_t base = (size_t)b * G4 + h;
    float gi = gA[base]            + gB[base]            + bias[h];
    float gf = gA[base + HID]      + gB[base + HID]      + bias[HID + h];
    float gg = gA[base + 2 * HID]  + gB[base + 2 * HID]  + bias[2 * HID + h];
    float go = gA[base + 3 * HID]  + gB[base + 3 * HID]  + bias[3 * HID + h];
    float ii = 1.f / (1.f + expf(-gi));
    float ff = 1.f / (1.f + expf(-gf));
    float tg = tanhf(gg);
    float oo = 1.f / (1.f + expf(-go));
    float cn = ff * c[i] + ii * tg;
    float hn = oo * tanhf(cn);
    c[i] = cn;
    short hb = f2b(hn);
    d1[(size_t)b * ld1 + h] = hb;
    d2[(size_t)b * ld2 + h] = hb;
}

// ---------------- softmax over the batch axis (dim 0) ----------------
__global__ void softmax_b(const float* __restrict__ logits, float* __restrict__ out,
                          short* __restrict__ z2, int t)
{
    __shared__ float red[8][32];
    int dl = threadIdx.x & 31;
    int bg = threadIdx.x >> 5;                 // 0..7, each covers 32 batch rows
    int d  = blockIdx.x * 32 + dl;
    bool valid = d < DICT;

    float m = -1e30f;
    if (valid)
        for (int i = 0; i < 32; ++i)
            m = fmaxf(m, logits[(size_t)(bg * 32 + i) * DICT + d]);
    red[bg][dl] = m;
    __syncthreads();
    float mm = red[0][dl];
    for (int r = 1; r < 8; ++r) mm = fmaxf(mm, red[r][dl]);
    __syncthreads();

    float s = 0.f;
    if (valid)
        for (int i = 0; i < 32; ++i)
            s += expf(logits[(size_t)(bg * 32 + i) * DICT + d] - mm);
    red[bg][dl] = s;
    __syncthreads();
    float ss = 0.f;
    for (int r = 0; r < 8; ++r) ss += red[r][dl];
    float inv = 1.f / ss;

    if (valid)
        for (int i = 0; i < 32; ++i) {
            int b = bg * 32 + i;
            float y = expf(logits[(size_t)b * DICT + d] - mm) * inv;
            out[(size_t)b * (TT * DICT) + (size_t)t * DICT + d] = y;
            z2[(size_t)b * K2P + d] = f2b(y);
        }
}

// ---------------- host ----------------
extern "C" void kernel_launch(void* const* d_in, const int* in_sizes, int n_in,
                              void* d_out, int out_size, void* d_ws, size_t ws_size,
                              hipStream_t stream)
{
    const float* x      = (const float*)d_in[0];
    const float* h1     = (const float*)d_in[1];
    const float* h2     = (const float*)d_in[2];
    const float* c1in   = (const float*)d_in[3];
    const float* c2in   = (const float*)d_in[4];
    const float* layW   = (const float*)d_in[5];
    const float* layb   = (const float*)d_in[6];
    const float* Wih1   = (const float*)d_in[7];
    const float* Whh1   = (const float*)d_in[8];
    const float* bih1   = (const float*)d_in[9];
    const float* bhh1   = (const float*)d_in[10];
    const float* Wih2   = (const float*)d_in[11];
    const float* Whh2   = (const float*)d_in[12];
    const float* bih2   = (const float*)d_in[13];
    const float* bhh2   = (const float*)d_in[14];
    const float* outW   = (const float*)d_in[15];
    const float* outb   = (const float*)d_in[16];
    float* out = (float*)d_out;

    char* ws = (char*)d_ws;
    size_t off = 0;
    auto alloc = [&](size_t bytes) { size_t p = off; off = (off + bytes + 255) & ~(size_t)255; return p; };

    short* w1cat = (short*)(ws + alloc((size_t)G4 * K1 * 2));
    short* w2cat = (short*)(ws + alloc((size_t)G4 * K2P * 2));
    short* outwb = (short*)(ws + alloc((size_t)DICT * HID * 2));
    short* laywb = (short*)(ws + alloc((size_t)HID * HID * 2));
    short* xp    = (short*)(ws + alloc((size_t)TT * BB * HID * 2));
    short* z1    = (short*)(ws + alloc((size_t)BB * K1 * 2));
    short* z2    = (short*)(ws + alloc((size_t)BB * K2P * 2));
    short* h2bf  = (short*)(ws + alloc((size_t)BB * HID * 2));
    float* g1    = (float*)(ws + alloc((size_t)2 * BB * G4 * 4));
    float* g2    = (float*)(ws + alloc((size_t)2 * BB * G4 * 4));
    float* lgts  = (float*)(ws + alloc((size_t)BB * DICT * 4));
    float* c1    = (float*)(ws + alloc((size_t)BB * HID * 4));
    float* c2    = (float*)(ws + alloc((size_t)BB * HID * 4));
    float* bias1 = (float*)(ws + alloc((size_t)G4 * 4));
    float* bias2 = (float*)(ws + alloc((size_t)G4 * 4));
    (void)ws_size; (void)n_in; (void)in_sizes; (void)out_size;

    // ---- weight prep (every call; deterministic) ----
    prep_w1<<<2048, 256, 0, stream>>>(Wih1, Whh1, w1cat);
    prep_w2<<<4096, 256, 0, stream>>>(Wih2, Whh2, w2cat);
    prep_cvt<<<2048, 256, 0, stream>>>(outW, outwb, (size_t)DICT * HID);
    prep_cvt<<<1024, 256, 0, stream>>>(layW, laywb, (size_t)HID * HID);
    prep_addv<<<16, 256, 0, stream>>>(bih1, bhh1, bias1, G4);
    prep_addv<<<16, 256, 0, stream>>>(bih2, bhh2, bias2, G4);
    init_z1<<<(BB * K1 + 255) / 256, 256, 0, stream>>>(h1, z1);
    init_z2<<<(BB * K2P + 255) / 256, 256, 0, stream>>>(h2, z2);
    hipMemcpyAsync(c1, c1in, (size_t)BB * HID * 4, hipMemcpyDeviceToDevice, stream);
    hipMemcpyAsync(c2, c2in, (size_t)BB * HID * 4, hipMemcpyDeviceToDevice, stream);

    // ---- input projection: xp[t][b][:] = x[b,t,:] @ layW^T + layb (stored bf16) ----
    gemm_nt<1, 1><<<dim3(16, (BB * TT) / 64, 1), 256, 0, stream>>>(
        x, HID, laywb, HID, layb, xp, 0, HID, BB * TT, HID, HID);

    long long gpart = (long long)BB * G4;

    for (int t = 0; t < TT; ++t) {
        copy_xt<<<(BB * HID + 255) / 256, 256, 0, stream>>>(xp, z1, t);

        // gates1 = z1 @ w1cat^T   (K-split 2)
        gemm_nt<0, 0><<<dim3(63, 4, 2), 256, 0, stream>>>(
            z1, K1, w1cat, K1, nullptr, g1, gpart, G4, BB, G4, K1);
        lstm_ew<<<(BB * HID + 255) / 256, 256, 0, stream>>>(
            g1, g1 + gpart, bias1, c1, z2 + DICT + HID, K2P, z1 + HID, K1);

        // gates2 = z2 @ w2cat^T   (K-split 2)
        gemm_nt<0, 0><<<dim3(63, 4, 2), 256, 0, stream>>>(
            z2, K2P, w2cat, K2P, nullptr, g2, gpart, G4, BB, G4, K2P);
        lstm_ew<<<(BB * HID + 255) / 256, 256, 0, stream>>>(
            g2, g2 + gpart, bias2, c2, z2 + DICT, K2P, h2bf, HID);

        // logits = h2 @ outW^T + outb
        gemm_nt<0, 0><<<dim3(76, 4, 1), 256, 0, stream>>>(
            h2bf, HID, outwb, HID, outb, lgts, 0, DICT, BB, DICT, HID);

        softmax_b<<<(DICT + 31) / 32, 256, 0, stream>>>(lgts, out, z2, t);
    }
}

// Round 2
// 4155.050 us; speedup vs baseline: 1.3783x; 1.3783x over previous
//
#include <hip/hip_runtime.h>
#include <hip/hip_bf16.h>

#define HID   1000
#define DICT  4811
#define TT    44
#define BB    256
#define G4    4000
#define G4P   4096
#define K1P   2048
#define K2P   6912
#define HP    1024
#define DP    4864
#define Z2_H2 4864
#define Z2_H1 5888

typedef __attribute__((ext_vector_type(8))) short short8;
typedef __attribute__((ext_vector_type(4))) float f32x4;

__device__ __forceinline__ short f2b(float f) {
    unsigned u = __float_as_uint(f);
    unsigned r = (u + 0x7FFFu + ((u >> 16) & 1u)) >> 16;
    return (short)r;
}

__device__ __forceinline__ void gload16(const void* g, const short* l) {
    __builtin_amdgcn_global_load_lds(
        (const __attribute__((address_space(1))) unsigned int*)g,
        (__attribute__((address_space(3))) unsigned int*)l, 16, 0, 0);
}

// ---------------- prep kernels ----------------
__global__ void prep_w1p(const float* __restrict__ wih1, const float* __restrict__ whh1,
                         short* __restrict__ w) {
    for (size_t i = (size_t)blockIdx.x * blockDim.x + threadIdx.x; i < (size_t)G4P * K1P;
         i += (size_t)gridDim.x * blockDim.x) {
        int n = (int)(i >> 11), j = (int)(i & 2047);
        float v = 0.f;
        if (n < G4) {
            if (j < HID) v = wih1[(size_t)n * 2000 + j];
            else if (j >= 1024 && j < 1024 + HID) {
                int jj = j - 1024;
                v = wih1[(size_t)n * 2000 + HID + jj] + whh1[(size_t)n * HID + jj];
            }
        }
        w[i] = f2b(v);
    }
}

__global__ void prep_w2p(const float* __restrict__ wih2, const float* __restrict__ whh2,
                         short* __restrict__ w) {
    int n = blockIdx.y;
    int j = blockIdx.x * 256 + threadIdx.x;
    float v = 0.f;
    if (n < G4) {
        if (j < DICT) v = wih2[(size_t)n * 6811 + j];
        else if (j >= Z2_H2 && j < Z2_H2 + HID) {
            int jj = j - Z2_H2;
            v = wih2[(size_t)n * 6811 + DICT + jj] + whh2[(size_t)n * HID + jj];
        } else if (j >= Z2_H1 && j < Z2_H1 + HID) {
            int jj = j - Z2_H1;
            v = wih2[(size_t)n * 6811 + DICT + HID + jj];
        }
    }
    w[(size_t)n * K2P + j] = f2b(v);
}

__global__ void prep_outwp(const float* __restrict__ outw, short* __restrict__ w) {
    int n = blockIdx.y;
    int j = blockIdx.x * 256 + threadIdx.x;
    float v = (n < DICT && j < HID) ? outw[(size_t)n * HID + j] : 0.f;
    w[(size_t)n * HP + j] = f2b(v);
}

__global__ void prep_cvt(const float* __restrict__ src, short* __restrict__ dst, size_t n) {
    for (size_t i = (size_t)blockIdx.x * blockDim.x + threadIdx.x; i < n;
         i += (size_t)gridDim.x * blockDim.x)
        dst[i] = f2b(src[i]);
}

__global__ void prep_addv(const float* __restrict__ a, const float* __restrict__ b,
                          float* __restrict__ dst, int n) {
    int i = blockIdx.x * blockDim.x + threadIdx.x;
    if (i < n) dst[i] = a[i] + b[i];
}

__global__ void init_vec(const float* __restrict__ src, short* __restrict__ dst, int ld) {
    int i = blockIdx.x * blockDim.x + threadIdx.x;
    if (i >= BB * HID) return;
    int b = i / HID, h = i % HID;
    dst[(size_t)b * ld + h] = f2b(src[i]);
}

// ---------------- xp projection GEMM (round-0 kernel, EPI=1/AF32=1 only) ----------------
template <int EPI, int AF32>
__global__ __launch_bounds__(256) void gemm_nt(
    const void* __restrict__ Ap, int lda,
    const short* __restrict__ Bp, int ldb,
    const float* __restrict__ bias,
    void* __restrict__ Cp, long long partStride, int ldc,
    int M, int N, int Kvalid)
{
    __shared__ short As[64][40];
    __shared__ short Bs[64][40];
    const int tid  = threadIdx.x;
    const int lane = tid & 63;
    const int wave = tid >> 6;
    const int wm = wave >> 1, wn = wave & 1;
    const int tm = blockIdx.y * 64, tn = blockIdx.x * 64;
    const int srow = tid >> 2;
    const int scol = (tid & 3) * 8;

    const int nk = (Kvalid + 31) >> 5;
    const int s0 = (int)(((long long)nk * blockIdx.z) / gridDim.z);
    const int s1 = (int)(((long long)nk * (blockIdx.z + 1)) / gridDim.z);

    const int arow = tm + srow;
    const int brow = tn + srow;
    const bool bvalid = brow < N;

    auto loadA = [&](int ks) -> short8 {
        int k = (ks << 5) + scol;
        short8 r = {0, 0, 0, 0, 0, 0, 0, 0};
        if (k + 8 <= Kvalid) {
            if (AF32) {
                const f32x4* p = (const f32x4*)((const float*)Ap + (size_t)arow * lda + k);
                f32x4 u0 = p[0], u1 = p[1];
                r[0] = f2b(u0[0]); r[1] = f2b(u0[1]); r[2] = f2b(u0[2]); r[3] = f2b(u0[3]);
                r[4] = f2b(u1[0]); r[5] = f2b(u1[1]); r[6] = f2b(u1[2]); r[7] = f2b(u1[3]);
            } else {
                r = *(const short8*)((const short*)Ap + (size_t)arow * lda + k);
            }
        }
        return r;
    };
    auto loadB = [&](int ks) -> short8 {
        int k = (ks << 5) + scol;
        short8 r = {0, 0, 0, 0, 0, 0, 0, 0};
        if (bvalid && (k + 8 <= Kvalid))
            r = *(const short8*)(Bp + (size_t)brow * ldb + k);
        return r;
    };

    f32x4 acc[2][2];
    for (int a = 0; a < 2; ++a)
        for (int b = 0; b < 2; ++b)
            acc[a][b] = (f32x4){0.f, 0.f, 0.f, 0.f};

    short8 ra = loadA(s0), rb = loadB(s0);
    *(short8*)&As[srow][scol] = ra;
    *(short8*)&Bs[srow][scol] = rb;
    __syncthreads();

    const int kg = (lane >> 4) * 8;
    const int fr = lane & 15;

    for (int s = s0; s < s1; ++s) {
        short8 a0 = *(short8*)&As[wm * 32 + fr][kg];
        short8 a1 = *(short8*)&As[wm * 32 + 16 + fr][kg];
        short8 b0 = *(short8*)&Bs[wn * 32 + fr][kg];
        short8 b1 = *(short8*)&Bs[wn * 32 + 16 + fr][kg];
        short8 na, nb;
        if (s + 1 < s1) { na = loadA(s + 1); nb = loadB(s + 1); }
        acc[0][0] = __builtin_amdgcn_mfma_f32_16x16x32_bf16(a0, b0, acc[0][0], 0, 0, 0);
        acc[0][1] = __builtin_amdgcn_mfma_f32_16x16x32_bf16(a0, b1, acc[0][1], 0, 0, 0);
        acc[1][0] = __builtin_amdgcn_mfma_f32_16x16x32_bf16(a1, b0, acc[1][0], 0, 0, 0);
        acc[1][1] = __builtin_amdgcn_mfma_f32_16x16x32_bf16(a1, b1, acc[1][1], 0, 0, 0);
        __syncthreads();
        if (s + 1 < s1) {
            *(short8*)&As[srow][scol] = na;
            *(short8*)&Bs[srow][scol] = nb;
        }
        __syncthreads();
    }

    float* Cf = (float*)Cp + (size_t)partStride * blockIdx.z;
    for (int mi = 0; mi < 2; ++mi)
        for (int ni = 0; ni < 2; ++ni) {
            int col = tn + wn * 32 + ni * 16 + (lane & 15);
            if (col >= N) continue;
            float bv = bias ? bias[col] : 0.f;
            int row0 = tm + wm * 32 + mi * 16 + ((lane >> 4) << 2);
            f32x4 v = acc[mi][ni];
            for (int j = 0; j < 4; ++j) {
                int row = row0 + j;
                float val = v[j] + bv;
                if (EPI == 0) {
                    Cf[(size_t)row * ldc + col] = val;
                } else {
                    int b = row / TT, t = row % TT;
                    ((short*)Cp)[((size_t)t * BB + b) * ldc + col] = f2b(val);
                }
            }
        }
}

// ---------------- step GEMM: C[256,N] = A[256,K] * B[N,K]^T, full-M tile ----------------
// tile 256x64, 8 waves (4M x 2N, wave-tile 64x32), global_load_lds staging,
// double-buffered LDS, XOR bank swizzle (slot ^ ((row>>1)&3)) applied on both
// source addresses (stage) and read addresses.
__global__ __launch_bounds__(512) void gemm_step(
    const short* __restrict__ A0, const short* __restrict__ A1, int splitK, int lda,
    const short* __restrict__ Bw, int ldb,
    float* __restrict__ C, long long partStride, int ldc, int nk)
{
    __shared__ __align__(16) short smem[2][10240];   // [A 8192 | B 2048] shorts per buffer
    const int tid  = threadIdx.x;
    const int lane = tid & 63;
    const int w    = tid >> 6;
    const int wm = w >> 1, wn = w & 1;
    const int tn = blockIdx.x * 64;
    const int s0 = (int)(((long long)nk * blockIdx.z) / gridDim.z);
    const int s1 = (int)(((long long)nk * (blockIdx.z + 1)) / gridDim.z);

    // staging: A slots 0..1023 (4x16B per 64B row, 256 rows), B slots 0..255 (64 rows)
    const int sA0 = w * 128 + lane;
    const int sA1 = sA0 + 64;
    const int rA0 = sA0 >> 2, rA1 = sA1 >> 2;
    const size_t aoff0 = (size_t)rA0 * lda + (((sA0 & 3) ^ ((rA0 >> 1) & 3)) << 3);
    const size_t aoff1 = (size_t)rA1 * lda + (((sA1 & 3) ^ ((rA1 >> 1) & 3)) << 3);
    const bool doB = (w < 4);
    const int sB = w * 64 + lane;
    const int rB = sB >> 2;
    const size_t boff = (size_t)(tn + rB) * ldb + (((sB & 3) ^ ((rB >> 1) & 3)) << 3);

    auto stage = [&](int buf, int s) {
        const int k0 = s << 5;
        const short* As = (k0 < splitK) ? A0 : A1;
        const short* lA = &smem[buf][0];
        gload16(As + k0 + aoff0, lA + w * 1024);
        gload16(As + k0 + aoff1, lA + w * 1024 + 512);
        if (doB) gload16(Bw + k0 + boff, lA + 8192 + w * 512);
    };

    // read offsets (shorts)
    const int fr  = lane & 15;
    const int kgs = ((lane >> 4) << 3) ^ (((lane >> 1) & 3) << 3);
    const int aRd = (wm * 64 + fr) * 32 + kgs;
    const int bRd = 8192 + (wn * 32 + fr) * 32 + kgs;

    f32x4 acc[4][2];
    #pragma unroll
    for (int a = 0; a < 4; ++a)
        #pragma unroll
        for (int b = 0; b < 2; ++b)
            acc[a][b] = (f32x4){0.f, 0.f, 0.f, 0.f};

    stage(0, s0);
    __syncthreads();
    int cur = 0;
    for (int s = s0; s < s1; ++s) {
        if (s + 1 < s1) stage(cur ^ 1, s + 1);
        const short* bp = &smem[cur][0];
        short8 a0 = *(const short8*)(bp + aRd);
        short8 a1 = *(const short8*)(bp + aRd + 512);
        short8 a2 = *(const short8*)(bp + aRd + 1024);
        short8 a3 = *(const short8*)(bp + aRd + 1536);
        short8 b0 = *(const short8*)(bp + bRd);
        short8 b1 = *(const short8*)(bp + bRd + 512);
        acc[0][0] = __builtin_amdgcn_mfma_f32_16x16x32_bf16(a0, b0, acc[0][0], 0, 0, 0);
        acc[1][0] = __builtin_amdgcn_mfma_f32_16x16x32_bf16(a1, b0, acc[1][0], 0, 0, 0);
        acc[2][0] = __builtin_amdgcn_mfma_f32_16x16x32_bf16(a2, b0, acc[2][0], 0, 0, 0);
        acc[3][0] = __builtin_amdgcn_mfma_f32_16x16x32_bf16(a3, b0, acc[3][0], 0, 0, 0);
        acc[0][1] = __builtin_amdgcn_mfma_f32_16x16x32_bf16(a0, b1, acc[0][1], 0, 0, 0);
        acc[1][1] = __builtin_amdgcn_mfma_f32_16x16x32_bf16(a1, b1, acc[1][1], 0, 0, 0);
        acc[2][1] = __builtin_amdgcn_mfma_f32_16x16x32_bf16(a2, b1, acc[2][1], 0, 0, 0);
        acc[3][1] = __builtin_amdgcn_mfma_f32_16x16x32_bf16(a3, b1, acc[3][1], 0, 0, 0);
        __syncthreads();
        cur ^= 1;
    }

    float* Cp = C + (size_t)partStride * blockIdx.z;
    const int colb = tn + wn * 32 + fr;
    const int rowb = wm * 64 + ((lane >> 4) << 2);
    #pragma unroll
    for (int mi = 0; mi < 4; ++mi)
        #pragma unroll
        for (int ni = 0; ni < 2; ++ni) {
            int col = colb + ni * 16;
            int row0 = rowb + mi * 16;
            #pragma unroll
            for (int j = 0; j < 4; ++j)
                Cp[(size_t)(row0 + j) * ldc + col] = acc[mi][ni][j];
        }
}

// ---------------- LSTM elementwise: sum 4 K-split parts + bias, cell, dual bf16 out ----
__global__ void lstm_ew4(const float* __restrict__ g, long long ps,
                         const float* __restrict__ bias, float* __restrict__ c,
                         short* __restrict__ d1, int ld1,
                         short* __restrict__ d2, int ld2)
{
    int i = blockIdx.x * blockDim.x + threadIdx.x;
    if (i >= BB * HID) return;
    int b = i / HID, h = i % HID;
    size_t base = (size_t)b * G4P + h;
    float gi = bias[h], gf = bias[HID + h], gg = bias[2 * HID + h], go = bias[3 * HID + h];
    #pragma unroll
    for (int p = 0; p < 4; ++p) {
        const float* gp = g + (size_t)ps * p + base;
        gi += gp[0];
        gf += gp[HID];
        gg += gp[2 * HID];
        go += gp[3 * HID];
    }
    float ii = 1.f / (1.f + expf(-gi));
    float ff = 1.f / (1.f + expf(-gf));
    float tg = tanhf(gg);
    float oo = 1.f / (1.f + expf(-go));
    float cn = ff * c[i] + ii * tg;
    c[i] = cn;
    float hn = oo * tanhf(cn);
    short hb = f2b(hn);
    d1[(size_t)b * ld1 + h] = hb;
    d2[(size_t)b * ld2 + h] = hb;
}

// ---------------- softmax over batch axis, sums 3 K-split logit parts + bias ----------
__global__ __launch_bounds__(256) void softmax3(
    const float* __restrict__ lg, long long ps, const float* __restrict__ outb,
    float* __restrict__ out, short* __restrict__ z2, int t)
{
    __shared__ float red[8][32];
    const int dl = threadIdx.x & 31;
    const int bg = threadIdx.x >> 5;
    const int d = blockIdx.x * 32 + dl;
    const bool valid = d < DICT;
    float v[32];
    float m = -1e30f;
    if (valid) {
        const float bv = outb[d];
        #pragma unroll
        for (int i = 0; i < 32; ++i) {
            size_t o = (size_t)(bg * 32 + i) * DP + d;
            float x = lg[o] + lg[ps + o] + lg[2 * ps + o] + bv;
            v[i] = x;
            m = fmaxf(m, x);
        }
    } else {
        #pragma unroll
        for (int i = 0; i < 32; ++i) v[i] = 0.f;
    }
    red[bg][dl] = m;
    __syncthreads();
    m = red[0][dl];
    #pragma unroll
    for (int r = 1; r < 8; ++r) m = fmaxf(m, red[r][dl]);
    float s = 0.f;
    #pragma unroll
    for (int i = 0; i < 32; ++i) { v[i] = expf(v[i] - m); s += v[i]; }
    __syncthreads();
    red[bg][dl] = s;
    __syncthreads();
    s = 0.f;
    #pragma unroll
    for (int r = 0; r < 8; ++r) s += red[r][dl];
    const float inv = 1.f / s;
    if (valid) {
        #pragma unroll
        for (int i = 0; i < 32; ++i) {
            int b = bg * 32 + i;
            float y = v[i] * inv;
            out[(size_t)b * ((size_t)TT * DICT) + (size_t)t * DICT + d] = y;
            z2[(size_t)b * K2P + d] = f2b(y);
        }
    }
}

// ---------------- host ----------------
extern "C" void kernel_launch(void* const* d_in, const int* in_sizes, int n_in,
                              void* d_out, int out_size, void* d_ws, size_t ws_size,
                              hipStream_t stream)
{
    const float* x    = (const float*)d_in[0];
    const float* h1   = (const float*)d_in[1];
    const float* h2   = (const float*)d_in[2];
    const float* c1in = (const float*)d_in[3];
    const float* c2in = (const float*)d_in[4];
    const float* layW = (const float*)d_in[5];
    const float* layb = (const float*)d_in[6];
    const float* Wih1 = (const float*)d_in[7];
    const float* Whh1 = (const float*)d_in[8];
    const float* bih1 = (const float*)d_in[9];
    const float* bhh1 = (const float*)d_in[10];
    const float* Wih2 = (const float*)d_in[11];
    const float* Whh2 = (const float*)d_in[12];
    const float* bih2 = (const float*)d_in[13];
    const float* bhh2 = (const float*)d_in[14];
    const float* outW = (const float*)d_in[15];
    const float* outb = (const float*)d_in[16];
    float* out = (float*)d_out;
    (void)in_sizes; (void)n_in; (void)out_size; (void)ws_size;

    char* ws = (char*)d_ws;
    size_t off = 0;
    auto alloc = [&](size_t bytes) -> void* {
        size_t p = off;
        off = (off + bytes + 255) & ~(size_t)255;
        return (void*)(ws + p);
    };

    short* w1cat = (short*)alloc((size_t)G4P * K1P * 2);
    short* w2cat = (short*)alloc((size_t)G4P * K2P * 2);
    short* outwb = (short*)alloc((size_t)DP * HP * 2);
    short* laywb = (short*)alloc((size_t)HID * HID * 2);
    short* xp    = (short*)alloc((size_t)TT * BB * HP * 2);
    short* h1pad = (short*)alloc((size_t)BB * HP * 2);
    short* h2pad = (short*)alloc((size_t)BB * HP * 2);
    short* z2    = (short*)alloc((size_t)BB * K2P * 2);
    float* gbuf  = (float*)alloc((size_t)4 * BB * G4P * 4);
    float* lgtp  = (float*)alloc((size_t)3 * BB * DP * 4);
    float* c1    = (float*)alloc((size_t)BB * HID * 4);
    float* c2    = (float*)alloc((size_t)BB * HID * 4);
    float* bias1 = (float*)alloc((size_t)G4 * 4);
    float* bias2 = (float*)alloc((size_t)G4 * 4);

    hipMemsetAsync(xp, 0, (size_t)TT * BB * HP * 2, stream);
    hipMemsetAsync(z2, 0, (size_t)BB * K2P * 2, stream);
    hipMemsetAsync(h1pad, 0, (size_t)BB * HP * 2, stream);
    hipMemsetAsync(h2pad, 0, (size_t)BB * HP * 2, stream);

    prep_w1p<<<4096, 256, 0, stream>>>(Wih1, Whh1, w1cat);
    prep_w2p<<<dim3(27, G4P), 256, 0, stream>>>(Wih2, Whh2, w2cat);
    prep_outwp<<<dim3(4, DP), 256, 0, stream>>>(outW, outwb);
    prep_cvt<<<1024, 256, 0, stream>>>(layW, laywb, (size_t)HID * HID);
    prep_addv<<<16, 256, 0, stream>>>(bih1, bhh1, bias1, G4);
    prep_addv<<<16, 256, 0, stream>>>(bih2, bhh2, bias2, G4);
    init_vec<<<1000, 256, 0, stream>>>(h1, h1pad, HP);
    init_vec<<<1000, 256, 0, stream>>>(h2, h2pad, HP);
    init_vec<<<1000, 256, 0, stream>>>(h2, z2 + Z2_H2, K2P);
    hipMemcpyAsync(c1, c1in, (size_t)BB * HID * 4, hipMemcpyDeviceToDevice, stream);
    hipMemcpyAsync(c2, c2in, (size_t)BB * HID * 4, hipMemcpyDeviceToDevice, stream);

    // input projection -> xp[t][b][0:1000] (bf16, stride 1024, pads stay zero)
    gemm_nt<1, 1><<<dim3(16, (BB * TT) / 64, 1), 256, 0, stream>>>(
        x, HID, laywb, HID, layb, xp, 0, HP, BB * TT, HID, HID);

    const long long GP = (long long)BB * G4P;
    const long long LP = (long long)BB * DP;

    for (int t = 0; t < TT; ++t) {
        // gates1 = [xp_t | h1] @ w1cat^T   (K-split 4)
        gemm_step<<<dim3(64, 1, 4), 512, 0, stream>>>(
            xp + (size_t)t * BB * HP, h1pad - HP, HP, HP, w1cat, K1P, gbuf, GP, G4P, K1P / 32);
        lstm_ew4<<<1000, 256, 0, stream>>>(gbuf, GP, bias1, c1, z2 + Z2_H1, K2P, h1pad, HP);

        // gates2 = z2 @ w2cat^T   (K-split 4)
        gemm_step<<<dim3(64, 1, 4), 512, 0, stream>>>(
            z2, z2, 0, K2P, w2cat, K2P, gbuf, GP, G4P, K2P / 32);
        lstm_ew4<<<1000, 256, 0, stream>>>(gbuf, GP, bias2, c2, z2 + Z2_H2, K2P, h2pad, HP);

        // logits = h2 @ outW^T   (K-split 3, bias folded into softmax)
        gemm_step<<<dim3(76, 1, 3), 512, 0, stream>>>(
            h2pad, h2pad, 0, HP, outwb, HP, lgtp, LP, DP, HP / 32);

        softmax3<<<151, 256, 0, stream>>>(lgtp, LP, outb, out, z2, t);
    }
}

// Round 3
// 3509.596 us; speedup vs baseline: 1.6318x; 1.1839x over previous
//
#include <hip/hip_runtime.h>
#include <hip/hip_bf16.h>

#define HID   1000
#define DICT  4811
#define TT    44
#define BB    256
#define G4    4000
#define G4P   4096
#define K1P   2048
#define K2P   6912
#define HP    1024
#define DP    4864
#define Z2_H2 4864
#define Z2_H1 5888
#define PD    3

typedef __attribute__((ext_vector_type(8))) short short8;
typedef __attribute__((ext_vector_type(4))) float f32x4;

__device__ __forceinline__ short f2b(float f) {
    unsigned u = __float_as_uint(f);
    unsigned r = (u + 0x7FFFu + ((u >> 16) & 1u)) >> 16;
    return (short)r;
}

__device__ __forceinline__ void gload16(const void* g, const short* l) {
    __builtin_amdgcn_global_load_lds(
        (const __attribute__((address_space(1))) unsigned int*)g,
        (__attribute__((address_space(3))) unsigned int*)l, 16, 0, 0);
}

// ---------------- prep kernels ----------------
__global__ void prep_w1p(const float* __restrict__ wih1, const float* __restrict__ whh1,
                         short* __restrict__ w) {
    for (size_t i = (size_t)blockIdx.x * blockDim.x + threadIdx.x; i < (size_t)G4P * K1P;
         i += (size_t)gridDim.x * blockDim.x) {
        int n = (int)(i >> 11), j = (int)(i & 2047);
        float v = 0.f;
        if (n < G4) {
            if (j < HID) v = wih1[(size_t)n * 2000 + j];
            else if (j >= 1024 && j < 1024 + HID) {
                int jj = j - 1024;
                v = wih1[(size_t)n * 2000 + HID + jj] + whh1[(size_t)n * HID + jj];
            }
        }
        w[i] = f2b(v);
    }
}

__global__ void prep_w2p(const float* __restrict__ wih2, const float* __restrict__ whh2,
                         short* __restrict__ w) {
    int n = blockIdx.y;
    int j = blockIdx.x * 256 + threadIdx.x;
    float v = 0.f;
    if (n < G4) {
        if (j < DICT) v = wih2[(size_t)n * 6811 + j];
        else if (j >= Z2_H2 && j < Z2_H2 + HID) {
            int jj = j - Z2_H2;
            v = wih2[(size_t)n * 6811 + DICT + jj] + whh2[(size_t)n * HID + jj];
        } else if (j >= Z2_H1 && j < Z2_H1 + HID) {
            int jj = j - Z2_H1;
            v = wih2[(size_t)n * 6811 + DICT + HID + jj];
        }
    }
    w[(size_t)n * K2P + j] = f2b(v);
}

__global__ void prep_outwp(const float* __restrict__ outw, short* __restrict__ w) {
    int n = blockIdx.y;
    int j = blockIdx.x * 256 + threadIdx.x;
    float v = (n < DICT && j < HID) ? outw[(size_t)n * HID + j] : 0.f;
    w[(size_t)n * HP + j] = f2b(v);
}

__global__ void prep_cvt(const float* __restrict__ src, short* __restrict__ dst, size_t n) {
    for (size_t i = (size_t)blockIdx.x * blockDim.x + threadIdx.x; i < n;
         i += (size_t)gridDim.x * blockDim.x)
        dst[i] = f2b(src[i]);
}

__global__ void prep_addv(const float* __restrict__ a, const float* __restrict__ b,
                          float* __restrict__ dst, int n) {
    int i = blockIdx.x * blockDim.x + threadIdx.x;
    if (i < n) dst[i] = a[i] + b[i];
}

__global__ void init_vec(const float* __restrict__ src, short* __restrict__ dst, int ld) {
    int i = blockIdx.x * blockDim.x + threadIdx.x;
    if (i >= BB * HID) return;
    int b = i / HID, h = i % HID;
    dst[(size_t)b * ld + h] = f2b(src[i]);
}

// ---------------- xp projection GEMM (runs once; round-0 kernel) ----------------
template <int EPI, int AF32>
__global__ __launch_bounds__(256) void gemm_nt(
    const void* __restrict__ Ap, int lda,
    const short* __restrict__ Bp, int ldb,
    const float* __restrict__ bias,
    void* __restrict__ Cp, long long partStride, int ldc,
    int M, int N, int Kvalid)
{
    __shared__ short As[64][40];
    __shared__ short Bs[64][40];
    const int tid  = threadIdx.x;
    const int lane = tid & 63;
    const int wave = tid >> 6;
    const int wm = wave >> 1, wn = wave & 1;
    const int tm = blockIdx.y * 64, tn = blockIdx.x * 64;
    const int srow = tid >> 2;
    const int scol = (tid & 3) * 8;

    const int nk = (Kvalid + 31) >> 5;
    const int s0 = (int)(((long long)nk * blockIdx.z) / gridDim.z);
    const int s1 = (int)(((long long)nk * (blockIdx.z + 1)) / gridDim.z);

    const int arow = tm + srow;
    const int brow = tn + srow;
    const bool bvalid = brow < N;

    auto loadA = [&](int ks) -> short8 {
        int k = (ks << 5) + scol;
        short8 r = {0, 0, 0, 0, 0, 0, 0, 0};
        if (k + 8 <= Kvalid) {
            if (AF32) {
                const f32x4* p = (const f32x4*)((const float*)Ap + (size_t)arow * lda + k);
                f32x4 u0 = p[0], u1 = p[1];
                r[0] = f2b(u0[0]); r[1] = f2b(u0[1]); r[2] = f2b(u0[2]); r[3] = f2b(u0[3]);
                r[4] = f2b(u1[0]); r[5] = f2b(u1[1]); r[6] = f2b(u1[2]); r[7] = f2b(u1[3]);
            } else {
                r = *(const short8*)((const short*)Ap + (size_t)arow * lda + k);
            }
        }
        return r;
    };
    auto loadB = [&](int ks) -> short8 {
        int k = (ks << 5) + scol;
        short8 r = {0, 0, 0, 0, 0, 0, 0, 0};
        if (bvalid && (k + 8 <= Kvalid))
            r = *(const short8*)(Bp + (size_t)brow * ldb + k);
        return r;
    };

    f32x4 acc[2][2];
    for (int a = 0; a < 2; ++a)
        for (int b = 0; b < 2; ++b)
            acc[a][b] = (f32x4){0.f, 0.f, 0.f, 0.f};

    short8 ra = loadA(s0), rb = loadB(s0);
    *(short8*)&As[srow][scol] = ra;
    *(short8*)&Bs[srow][scol] = rb;
    __syncthreads();

    const int kg = (lane >> 4) * 8;
    const int fr = lane & 15;

    for (int s = s0; s < s1; ++s) {
        short8 a0 = *(short8*)&As[wm * 32 + fr][kg];
        short8 a1 = *(short8*)&As[wm * 32 + 16 + fr][kg];
        short8 b0 = *(short8*)&Bs[wn * 32 + fr][kg];
        short8 b1 = *(short8*)&Bs[wn * 32 + 16 + fr][kg];
        short8 na, nb;
        if (s + 1 < s1) { na = loadA(s + 1); nb = loadB(s + 1); }
        acc[0][0] = __builtin_amdgcn_mfma_f32_16x16x32_bf16(a0, b0, acc[0][0], 0, 0, 0);
        acc[0][1] = __builtin_amdgcn_mfma_f32_16x16x32_bf16(a0, b1, acc[0][1], 0, 0, 0);
        acc[1][0] = __builtin_amdgcn_mfma_f32_16x16x32_bf16(a1, b0, acc[1][0], 0, 0, 0);
        acc[1][1] = __builtin_amdgcn_mfma_f32_16x16x32_bf16(a1, b1, acc[1][1], 0, 0, 0);
        __syncthreads();
        if (s + 1 < s1) {
            *(short8*)&As[srow][scol] = na;
            *(short8*)&Bs[srow][scol] = nb;
        }
        __syncthreads();
    }

    float* Cf = (float*)Cp + (size_t)partStride * blockIdx.z;
    for (int mi = 0; mi < 2; ++mi)
        for (int ni = 0; ni < 2; ++ni) {
            int col = tn + wn * 32 + ni * 16 + (lane & 15);
            if (col >= N) continue;
            float bv = bias ? bias[col] : 0.f;
            int row0 = tm + wm * 32 + mi * 16 + ((lane >> 4) << 2);
            f32x4 v = acc[mi][ni];
            for (int j = 0; j < 4; ++j) {
                int row = row0 + j;
                float val = v[j] + bv;
                if (EPI == 0) {
                    Cf[(size_t)row * ldc + col] = val;
                } else {
                    int b = row / TT, t = row % TT;
                    ((short*)Cp)[((size_t)t * BB + b) * ldc + col] = f2b(val);
                }
            }
        }
}

// ---------------- step GEMM v3: C[256,N] = A[256,K] * B[N,K]^T ----------------
// tile 256x128, 8 waves (4M x 2N, wave-tile 64x64), 3-deep global_load_lds
// pipeline with counted vmcnt (never 0 in steady state), raw s_barrier,
// XOR bank swizzle on both staging source and LDS reads.
__global__ __launch_bounds__(512) void gemm_step3(
    const short* __restrict__ A0, const short* __restrict__ A1, int splitA, int lda,
    const short* __restrict__ Bw, int ldb,
    float* __restrict__ C, long long partStride, int ldc, int nk)
{
    __shared__ __align__(16) short smem[PD][12288];   // per buf: A 16KB (8192 sh) | B 8KB (4096 sh)
    const int tid  = threadIdx.x;
    const int lane = tid & 63;
    const int w    = tid >> 6;
    const int wm = w >> 1, wn = w & 1;
    const int tn = blockIdx.x * 128;
    const int s0 = (int)(((long long)nk * blockIdx.z) / gridDim.z);
    const int s1 = (int)(((long long)nk * (blockIdx.z + 1)) / gridDim.z);

    // staging: A = 1024 16B-chunks (256 rows x 4), B = 512 chunks (128 rows x 4)
    const int cA0 = w * 64 + lane;
    const int cA1 = cA0 + 512;
    const int rA0 = cA0 >> 2, rA1 = cA1 >> 2;
    const size_t aoff0 = (size_t)rA0 * lda + (size_t)((((cA0 & 3) ^ ((rA0 >> 1) & 3))) << 3);
    const size_t aoff1 = (size_t)rA1 * lda + (size_t)((((cA1 & 3) ^ ((rA1 >> 1) & 3))) << 3);
    const int cB = w * 64 + lane;
    const int rB = cB >> 2;
    const size_t boff = (size_t)(tn + rB) * ldb + (size_t)((((cB & 3) ^ ((rB >> 1) & 3))) << 3);

    auto stage = [&](int buf, int s) {
        const int k0 = s << 5;
        const short* As = (k0 < splitA) ? A0 : A1;
        const short* l = &smem[buf][0];
        gload16(As + k0 + aoff0, l + w * 512);
        gload16(As + k0 + aoff1, l + 4096 + w * 512);
        gload16(Bw + k0 + boff,  l + 8192 + w * 512);
    };

    // LDS read offsets (shorts): frag row*32 + (chunk^swz)*8
    const int fr = lane & 15;
    const int kg = lane >> 4;                 // 0..3 = k-chunk of this lane's frag
    int aRd[4], bRd[4];
    #pragma unroll
    for (int mi = 0; mi < 4; ++mi) {
        int row = wm * 64 + mi * 16 + fr;
        aRd[mi] = row * 32 + ((kg ^ ((row >> 1) & 3)) << 3);
    }
    #pragma unroll
    for (int ni = 0; ni < 4; ++ni) {
        int row = wn * 64 + ni * 16 + fr;
        bRd[ni] = 8192 + row * 32 + ((kg ^ ((row >> 1) & 3)) << 3);
    }

    f32x4 acc[4][4];
    #pragma unroll
    for (int a = 0; a < 4; ++a)
        #pragma unroll
        for (int b = 0; b < 4; ++b)
            acc[a][b] = (f32x4){0.f, 0.f, 0.f, 0.f};

    #pragma unroll
    for (int i = 0; i < PD; ++i)
        if (s0 + i < s1) stage(i, s0 + i);

    int buf = 0;
    for (int s = s0; s < s1; ++s) {
        const int ahead = s1 - 1 - s;          // stages issued after s (3 loads each)
        if (ahead >= 2)      asm volatile("s_waitcnt vmcnt(6)" ::: "memory");
        else if (ahead == 1) asm volatile("s_waitcnt vmcnt(3)" ::: "memory");
        else                 asm volatile("s_waitcnt vmcnt(0)" ::: "memory");
        __builtin_amdgcn_s_barrier();          // buf now fully staged for all waves

        const short* bp = &smem[buf][0];
        short8 af[4], bf[4];
        #pragma unroll
        for (int i = 0; i < 4; ++i) af[i] = *(const short8*)(bp + aRd[i]);
        #pragma unroll
        for (int i = 0; i < 4; ++i) bf[i] = *(const short8*)(bp + bRd[i]);
        asm volatile("s_waitcnt lgkmcnt(0)" ::: "memory");   // frags in regs
        __builtin_amdgcn_sched_barrier(0);                   // rule 18: pin MFMAs below
        __builtin_amdgcn_s_barrier();          // all waves done reading buf
        if (s + PD < s1) stage(buf, s + PD);   // recycle buf

        #pragma unroll
        for (int mi = 0; mi < 4; ++mi)
            #pragma unroll
            for (int ni = 0; ni < 4; ++ni)
                acc[mi][ni] = __builtin_amdgcn_mfma_f32_16x16x32_bf16(af[mi], bf[ni], acc[mi][ni], 0, 0, 0);

        buf = (buf + 1 == PD) ? 0 : buf + 1;
    }

    float* Cp = C + (size_t)partStride * blockIdx.z;
    const int colb = tn + wn * 64 + fr;
    const int rowb = wm * 64 + (kg << 2);
    #pragma unroll
    for (int mi = 0; mi < 4; ++mi)
        #pragma unroll
        for (int ni = 0; ni < 4; ++ni) {
            int col = colb + ni * 16;
            int row0 = rowb + mi * 16;
            #pragma unroll
            for (int j = 0; j < 4; ++j)
                Cp[(size_t)(row0 + j) * ldc + col] = acc[mi][ni][j];
        }
}

// ---------------- LSTM elementwise: sum NP K-split parts + bias, cell, dual bf16 out ----
template <int NP>
__global__ void lstm_ewN(const float* __restrict__ g, long long ps,
                         const float* __restrict__ bias, float* __restrict__ c,
                         short* __restrict__ d1, int ld1,
                         short* __restrict__ d2, int ld2)
{
    int i = blockIdx.x * blockDim.x + threadIdx.x;
    if (i >= BB * HID) return;
    int b = i / HID, h = i % HID;
    size_t base = (size_t)b * G4P + h;
    float gi = bias[h], gf = bias[HID + h], gg = bias[2 * HID + h], go = bias[3 * HID + h];
    #pragma unroll
    for (int p = 0; p < NP; ++p) {
        const float* gp = g + (size_t)ps * p + base;
        gi += gp[0];
        gf += gp[HID];
        gg += gp[2 * HID];
        go += gp[3 * HID];
    }
    float ii = 1.f / (1.f + expf(-gi));
    float ff = 1.f / (1.f + expf(-gf));
    float tg = tanhf(gg);
    float oo = 1.f / (1.f + expf(-go));
    float cn = ff * c[i] + ii * tg;
    c[i] = cn;
    float hn = oo * tanhf(cn);
    short hb = f2b(hn);
    d1[(size_t)b * ld1 + h] = hb;
    d2[(size_t)b * ld2 + h] = hb;
}

// ---------------- softmax over batch axis, sums NP K-split logit parts + bias ----------
template <int NP>
__global__ __launch_bounds__(256) void softmaxN(
    const float* __restrict__ lg, long long ps, const float* __restrict__ outb,
    float* __restrict__ out, short* __restrict__ z2, int t)
{
    __shared__ float red[8][32];
    const int dl = threadIdx.x & 31;
    const int bg = threadIdx.x >> 5;
    const int d = blockIdx.x * 32 + dl;
    const bool valid = d < DICT;
    float v[32];
    float m = -1e30f;
    if (valid) {
        const float bv = outb[d];
        #pragma unroll
        for (int i = 0; i < 32; ++i) {
            size_t o = (size_t)(bg * 32 + i) * DP + d;
            float x = bv;
            #pragma unroll
            for (int p = 0; p < NP; ++p) x += lg[(size_t)ps * p + o];
            v[i] = x;
            m = fmaxf(m, x);
        }
    } else {
        #pragma unroll
        for (int i = 0; i < 32; ++i) v[i] = 0.f;
    }
    red[bg][dl] = m;
    __syncthreads();
    m = red[0][dl];
    #pragma unroll
    for (int r = 1; r < 8; ++r) m = fmaxf(m, red[r][dl]);
    float s = 0.f;
    #pragma unroll
    for (int i = 0; i < 32; ++i) { v[i] = expf(v[i] - m); s += v[i]; }
    __syncthreads();
    red[bg][dl] = s;
    __syncthreads();
    s = 0.f;
    #pragma unroll
    for (int r = 0; r < 8; ++r) s += red[r][dl];
    const float inv = 1.f / s;
    if (valid) {
        #pragma unroll
        for (int i = 0; i < 32; ++i) {
            int b = bg * 32 + i;
            float y = v[i] * inv;
            out[(size_t)b * ((size_t)TT * DICT) + (size_t)t * DICT + d] = y;
            z2[(size_t)b * K2P + d] = f2b(y);
        }
    }
}

// ---------------- host ----------------
extern "C" void kernel_launch(void* const* d_in, const int* in_sizes, int n_in,
                              void* d_out, int out_size, void* d_ws, size_t ws_size,
                              hipStream_t stream)
{
    const float* x    = (const float*)d_in[0];
    const float* h1   = (const float*)d_in[1];
    const float* h2   = (const float*)d_in[2];
    const float* c1in = (const float*)d_in[3];
    const float* c2in = (const float*)d_in[4];
    const float* layW = (const float*)d_in[5];
    const float* layb = (const float*)d_in[6];
    const float* Wih1 = (const float*)d_in[7];
    const float* Whh1 = (const float*)d_in[8];
    const float* bih1 = (const float*)d_in[9];
    const float* bhh1 = (const float*)d_in[10];
    const float* Wih2 = (const float*)d_in[11];
    const float* Whh2 = (const float*)d_in[12];
    const float* bih2 = (const float*)d_in[13];
    const float* bhh2 = (const float*)d_in[14];
    const float* outW = (const float*)d_in[15];
    const float* outb = (const float*)d_in[16];
    float* out = (float*)d_out;
    (void)in_sizes; (void)n_in; (void)out_size; (void)ws_size;

    char* ws = (char*)d_ws;
    size_t off = 0;
    auto alloc = [&](size_t bytes) -> void* {
        size_t p = off;
        off = (off + bytes + 255) & ~(size_t)255;
        return (void*)(ws + p);
    };

    short* w1cat = (short*)alloc((size_t)G4P * K1P * 2);
    short* w2cat = (short*)alloc((size_t)G4P * K2P * 2);
    short* outwb = (short*)alloc((size_t)DP * HP * 2);
    short* laywb = (short*)alloc((size_t)HID * HID * 2);
    short* xp    = (short*)alloc((size_t)TT * BB * HP * 2);
    short* h1pad = (short*)alloc((size_t)BB * HP * 2);
    short* h2pad = (short*)alloc((size_t)BB * HP * 2);
    short* z2    = (short*)alloc((size_t)BB * K2P * 2);
    float* gbuf  = (float*)alloc((size_t)8 * BB * G4P * 4);
    float* lgtp  = (float*)alloc((size_t)4 * BB * DP * 4);
    float* c1    = (float*)alloc((size_t)BB * HID * 4);
    float* c2    = (float*)alloc((size_t)BB * HID * 4);
    float* bias1 = (float*)alloc((size_t)G4 * 4);
    float* bias2 = (float*)alloc((size_t)G4 * 4);

    hipMemsetAsync(xp, 0, (size_t)TT * BB * HP * 2, stream);
    hipMemsetAsync(z2, 0, (size_t)BB * K2P * 2, stream);
    hipMemsetAsync(h1pad, 0, (size_t)BB * HP * 2, stream);
    hipMemsetAsync(h2pad, 0, (size_t)BB * HP * 2, stream);

    prep_w1p<<<4096, 256, 0, stream>>>(Wih1, Whh1, w1cat);
    prep_w2p<<<dim3(27, G4P), 256, 0, stream>>>(Wih2, Whh2, w2cat);
    prep_outwp<<<dim3(4, DP), 256, 0, stream>>>(outW, outwb);
    prep_cvt<<<1024, 256, 0, stream>>>(layW, laywb, (size_t)HID * HID);
    prep_addv<<<16, 256, 0, stream>>>(bih1, bhh1, bias1, G4);
    prep_addv<<<16, 256, 0, stream>>>(bih2, bhh2, bias2, G4);
    init_vec<<<1000, 256, 0, stream>>>(h1, h1pad, HP);
    init_vec<<<1000, 256, 0, stream>>>(h2, h2pad, HP);
    init_vec<<<1000, 256, 0, stream>>>(h2, z2 + Z2_H2, K2P);
    hipMemcpyAsync(c1, c1in, (size_t)BB * HID * 4, hipMemcpyDeviceToDevice, stream);
    hipMemcpyAsync(c2, c2in, (size_t)BB * HID * 4, hipMemcpyDeviceToDevice, stream);

    // input projection -> xp[t][b][0:1000] (bf16, stride 1024, pads stay zero)
    gemm_nt<1, 1><<<dim3(16, (BB * TT) / 64, 1), 256, 0, stream>>>(
        x, HID, laywb, HID, layb, xp, 0, HP, BB * TT, HID, HID);

    const long long GP = (long long)BB * G4P;
    const long long LP = (long long)BB * DP;

    for (int t = 0; t < TT; ++t) {
        // gates1 = [xp_t | h1] @ w1cat^T   (K-split 4, chunks of 16 ksteps)
        gemm_step3<<<dim3(32, 1, 4), 512, 0, stream>>>(
            xp + (size_t)t * BB * HP, h1pad - HP, 1024, HP, w1cat, K1P, gbuf, GP, G4P, K1P / 32);
        lstm_ewN<4><<<1000, 256, 0, stream>>>(gbuf, GP, bias1, c1, z2 + Z2_H1, K2P, h1pad, HP);

        // gates2 = z2 @ w2cat^T   (K-split 8, 27 ksteps each)
        gemm_step3<<<dim3(32, 1, 8), 512, 0, stream>>>(
            z2, z2, 0, K2P, w2cat, K2P, gbuf, GP, G4P, K2P / 32);
        lstm_ewN<8><<<1000, 256, 0, stream>>>(gbuf, GP, bias2, c2, z2 + Z2_H2, K2P, h2pad, HP);

        // logits = h2 @ outW^T   (K-split 4, 8 ksteps each; bias folded into softmax)
        gemm_step3<<<dim3(38, 1, 4), 512, 0, stream>>>(
            h2pad, h2pad, 0, HP, outwb, HP, lgtp, LP, DP, HP / 32);

        softmaxN<4><<<151, 256, 0, stream>>>(lgtp, LP, outb, out, z2, t);
    }
}